// Round 7
// baseline (246.991 us; speedup 1.0000x reference)
//
#include <hip/hip_runtime.h>

#define DEVFN __device__ __forceinline__

// NaN-propagating relu (fmaxf(NaN,0)==0 would mask upstream failures).
DEVFN float relu(float x) { return x < 0.f ? 0.f : x; }

// f16 pair helpers: weights/activations packed as half2 in k-major pairs.
// v_dot2_f32_f16: 2 MACs per instr, f32 accumulate.
typedef _Float16 h2 __attribute__((ext_vector_type(2)));
DEVFN float dot2(unsigned a, unsigned b, float c) {
    return __builtin_amdgcn_fdot2(__builtin_bit_cast(h2, a),
                                  __builtin_bit_cast(h2, b), c, false);
}
DEVFN unsigned pack2(float x, float y) {
    h2 h; h.x = (_Float16)x; h.y = (_Float16)y;
    return __builtin_bit_cast(unsigned, h);
}

// Packed-weight layout (round-7: TRANSPOSED for per-thread contiguity):
// W (K x C, k-major) -> PW[c*(K/2) + kp] = half2(W[2kp][c], W[2kp+1][c]).
// A thread owning col c reads K/2 CONTIGUOUS dwords -> uint4 loads, 4x fewer
// VMEM instructions than the scalar stride-512B streams of round 6.
// Offsets (in dwords) inside the packed-weight workspace region:
#define OFF_Q   0
#define OFF_K   8192
#define OFF_V   16384
#define OFF_O   24576
#define OFF_L1  32768
#define OFF_L2  49152
#define OFF_IN  65536
#define OFF_PE  69632
#define OFF_FU  73728
#define PACKED_TOTAL 79872

// ---------------------------------------------------------------------------
// K0: pack all weight matrices to half2 (runs once before ka).
// ---------------------------------------------------------------------------
__global__ __launch_bounds__(256) void k0_pack(
    const float* __restrict__ q_w, const float* __restrict__ k_w,
    const float* __restrict__ v_w, const float* __restrict__ o_w,
    const float* __restrict__ l1_w, const float* __restrict__ l2_w,
    const float* __restrict__ in_w, const float* __restrict__ pe_w2,
    const float* __restrict__ fu_w, unsigned* __restrict__ dst)
{
    const int gid = blockIdx.x * 256 + threadIdx.x;
    const int stride = gridDim.x * 256;
    auto packmat = [&](const float* s, int K, int C, unsigned* d) {
        const int kp2 = K / 2;
        const int n = kp2 * C;
        for (int i = gid; i < n; i += stride) {
            int c = i / kp2, kp = i - c * kp2;   // dst index = c*kp2 + kp
            d[i] = pack2(s[(2 * kp) * C + c], s[(2 * kp + 1) * C + c]);
        }
    };
    packmat(q_w, 128, 128, dst + OFF_Q);
    packmat(k_w, 128, 128, dst + OFF_K);
    packmat(v_w, 128, 128, dst + OFF_V);
    packmat(o_w, 128, 128, dst + OFF_O);
    packmat(l1_w, 128, 256, dst + OFF_L1);
    packmat(l2_w, 256, 128, dst + OFF_L2);
    packmat(in_w, 64, 128, dst + OFF_IN);
    packmat(pe_w2, 64, 128, dst + OFF_PE);
    packmat(fu_w, 192, 64, dst + OFF_FU);
}

// ---------------------------------------------------------------------------
// KA: fused pre-work, two block roles interleaved (bx%3): 2/3 src, 1/3 nbr.
//  src role : src = features@in_w+in_b + relu(pe)@pe_w2+pe_b2 ; qs/ks/vs
//  nbr role : neighbor top-16 (manhattan<=4, stable); nbr-block 0 zeros BN.
// Round-6 structure; weight streams now per-thread-contiguous uint4.
// ---------------------------------------------------------------------------
__global__ __launch_bounds__(256, 4) void ka_pre_cst(
    const float* __restrict__ features, const int* __restrict__ coords,
    const float* __restrict__ pe_w1, const float* __restrict__ pe_b1,
    const float* __restrict__ pe_b2,
    const float* __restrict__ in_b,
    const unsigned* __restrict__ wH,          // packed weights
    float* __restrict__ src,
    float* __restrict__ qs, float* __restrict__ ks, float* __restrict__ vs,
    int* __restrict__ nbr, float* __restrict__ bnAcc, int N)
{
    // src-role LDS
    __shared__ __align__(16) float S[1024];       // 8 x 128 src f32
    __shared__ __align__(16) unsigned SH[512];    // 8 x 64 src packed
    __shared__ __align__(16) unsigned FHp[256];   // 8 x 32 features packed
    __shared__ __align__(16) unsigned HHp[256];   // 8 x 32 pe-hidden packed
    __shared__ int   sC[24];
    // nbr-role LDS
    __shared__ int cnt[16];
    __shared__ int lst[16 * 64];
    __shared__ int outL[256];

    const int tid = threadIdx.x;
    const int bx = blockIdx.x;
    const int role_nbr = (bx % 3) == 2;

    if (role_nbr) {
        // ---------------- nbr role: neighbor search -----------------------
        const int nb = bx / 3;
        const int q0 = nb * 16;
        if (nb == 0 && tid < 128) bnAcc[tid] = 0.f;
        if (tid < 16) cnt[tid] = 0;
        outL[tid] = -1;
        __syncthreads();
        int qx[16], qy[16], qz[16];
#pragma unroll
        for (int q = 0; q < 16; ++q) {
            qx[q] = coords[(q0 + q) * 3 + 0];
            qy[q] = coords[(q0 + q) * 3 + 1];
            qz[q] = coords[(q0 + q) * 3 + 2];
        }
        for (int cd = tid; cd < N; cd += 256) {
            int cx = coords[cd * 3 + 0];
            int cy = coords[cd * 3 + 1];
            int cz = coords[cd * 3 + 2];
#pragma unroll
            for (int q = 0; q < 16; ++q) {
                int dx = cx - qx[q]; dx = dx < 0 ? -dx : dx;
                int dy = cy - qy[q]; dy = dy < 0 ? -dy : dy;
                int dz = cz - qz[q]; dz = dz < 0 ? -dz : dz;
                int d = dx + dy + dz;
                if (d <= 4) {
                    int s = atomicAdd(&cnt[q], 1);
                    if (s < 64) lst[q * 64 + s] = (d << 13) | cd;
                }
            }
        }
        __syncthreads();
        {
            const int q = tid >> 4, t = tid & 15;
            int n = cnt[q]; if (n > 64) n = 64;
            for (int e = t; e < n; e += 16) {
                int key = lst[q * 64 + e];
                int rank = 0;
                for (int j = 0; j < n; ++j) rank += (lst[q * 64 + j] < key) ? 1 : 0;
                if (rank < 16) outL[q * 16 + rank] = key & 8191;
            }
        }
        __syncthreads();
        {
            const int q = tid >> 4, t = tid & 15;
            nbr[(q0 + q) * 16 + t] = outL[q * 16 + t];
        }
        return;
    }

    // ---------------- src role: src + q/k/v projections -------------------
    const int sb = (bx / 3) * 2 + (bx % 3);   // 0..1023
    const int r0 = sb * 8;
    if (tid < 24) sC[tid] = coords[r0 * 3 + tid];
    if (tid < 256) {   // features 8x64 -> packed pairs
        float2 f = *(const float2*)(features + r0 * 64 + tid * 2);
        FHp[tid] = pack2(f.x, f.y);
    }
    __syncthreads();
    if (tid < 256) {   // pe hidden, 2 cols per thread, packed
        int r = tid >> 5, t2 = (tid & 31) * 2;
        float v0 = sC[r * 3 + 0] * (1.f / 95.f);
        float v1 = sC[r * 3 + 1] * (1.f / 95.f);
        float v2 = sC[r * 3 + 2] * (1.f / 95.f);
        float h0 = v0 * pe_w1[t2] + v1 * pe_w1[64 + t2] + v2 * pe_w1[128 + t2] + pe_b1[t2];
        float h1 = v0 * pe_w1[t2 + 1] + v1 * pe_w1[64 + t2 + 1] + v2 * pe_w1[128 + t2 + 1] + pe_b1[t2 + 1];
        HHp[tid] = pack2(relu(h0), relu(h1));
    }
    __syncthreads();
    const int c = tid & 127, rh = tid >> 7;
    {
        // src = F@in_w + H@pe_w2 + (in_b + pe_b2); contiguous uint4 weights
        const unsigned* inH = wH + OFF_IN + c * 32;   // K=64 -> 32 dwords
        const unsigned* peH = wH + OFF_PE + c * 32;
        float acc[4];
        const float base = in_b[c] + pe_b2[c];
#pragma unroll
        for (int r = 0; r < 4; ++r) acc[r] = base;
        for (int kp4 = 0; kp4 < 8; ++kp4) {
            uint4 wi = *(const uint4*)(inH + kp4 * 4);
            uint4 wp = *(const uint4*)(peH + kp4 * 4);
#pragma unroll
            for (int r = 0; r < 4; ++r) {
                const int rr = rh * 4 + r;
                uint4 f = *(const uint4*)(&FHp[rr * 32 + kp4 * 4]);
                uint4 h = *(const uint4*)(&HHp[rr * 32 + kp4 * 4]);
                acc[r] = dot2(f.x, wi.x, acc[r]); acc[r] = dot2(f.y, wi.y, acc[r]);
                acc[r] = dot2(f.z, wi.z, acc[r]); acc[r] = dot2(f.w, wi.w, acc[r]);
                acc[r] = dot2(h.x, wp.x, acc[r]); acc[r] = dot2(h.y, wp.y, acc[r]);
                acc[r] = dot2(h.z, wp.z, acc[r]); acc[r] = dot2(h.w, wp.w, acc[r]);
            }
        }
#pragma unroll
        for (int r = 0; r < 4; ++r) {
            src[(r0 + rh * 4 + r) * 128 + c] = acc[r];
            S[(rh * 4 + r) * 128 + c] = acc[r];
        }
    }
    __syncthreads();
    // pack S -> SH (pairs along the col axis, which is K for q/k/v)
    for (int i = tid; i < 512; i += 256) {
        float2 s = *(const float2*)(&S[i * 2]);
        SH[i] = pack2(s.x, s.y);
    }
    __syncthreads();
    // q/k/v in one pass: 3 contiguous uint4 weight streams, dot2
    {
        const unsigned* qH = wH + OFF_Q + c * 64;   // K=128 -> 64 dwords
        const unsigned* kH = wH + OFF_K + c * 64;
        const unsigned* vH = wH + OFF_V + c * 64;
        float aq[4], ak[4], av[4];
#pragma unroll
        for (int r = 0; r < 4; ++r) { aq[r] = 0.f; ak[r] = 0.f; av[r] = 0.f; }
        for (int kp4 = 0; kp4 < 16; ++kp4) {
            uint4 wq = *(const uint4*)(qH + kp4 * 4);
            uint4 wk = *(const uint4*)(kH + kp4 * 4);
            uint4 wv = *(const uint4*)(vH + kp4 * 4);
#pragma unroll
            for (int r = 0; r < 4; ++r) {
                uint4 s4 = *(const uint4*)(&SH[(rh * 4 + r) * 64 + kp4 * 4]);
                aq[r] = dot2(s4.x, wq.x, aq[r]); aq[r] = dot2(s4.y, wq.y, aq[r]);
                aq[r] = dot2(s4.z, wq.z, aq[r]); aq[r] = dot2(s4.w, wq.w, aq[r]);
                ak[r] = dot2(s4.x, wk.x, ak[r]); ak[r] = dot2(s4.y, wk.y, ak[r]);
                ak[r] = dot2(s4.z, wk.z, ak[r]); ak[r] = dot2(s4.w, wk.w, ak[r]);
                av[r] = dot2(s4.x, wv.x, av[r]); av[r] = dot2(s4.y, wv.y, av[r]);
                av[r] = dot2(s4.z, wv.z, av[r]); av[r] = dot2(s4.w, wv.w, av[r]);
            }
        }
#pragma unroll
        for (int r = 0; r < 4; ++r) {
            qs[(r0 + rh * 4 + r) * 128 + c] = aq[r];
            ks[(r0 + rh * 4 + r) * 128 + c] = ak[r];
            vs[(r0 + rh * 4 + r) * 128 + c] = av[r];
        }
    }
}

// ---------------------------------------------------------------------------
// K4: attention + o-proj + LN1 + FFN + LN2 + fusion + BN partials.
// Round-6 structure; weight streams per-thread-contiguous uint4.
// ---------------------------------------------------------------------------
DEVFN void ln_rows8_pack(float* Cb, unsigned* CHp, const float* __restrict__ g,
                         const float* __restrict__ b, int tid)
{
    const int r = tid >> 5, l = tid & 31;
    float x[4]; float s = 0.f, s2 = 0.f;
#pragma unroll
    for (int i = 0; i < 4; ++i) {
        x[i] = Cb[r * 128 + l * 4 + i];
        s += x[i]; s2 += x[i] * x[i];
    }
#pragma unroll
    for (int o = 1; o < 32; o <<= 1) { s += __shfl_xor(s, o); s2 += __shfl_xor(s2, o); }
    float mu = s * (1.f / 128.f);
    float var = s2 * (1.f / 128.f) - mu * mu;
    float rstd = rsqrtf(var + 1e-5f);
    float y[4];
#pragma unroll
    for (int i = 0; i < 4; ++i) {
        int cc = l * 4 + i;
        y[i] = (x[i] - mu) * rstd * g[cc] + b[cc];
        Cb[r * 128 + cc] = y[i];
    }
    CHp[r * 64 + l * 2]     = pack2(y[0], y[1]);
    CHp[r * 64 + l * 2 + 1] = pack2(y[2], y[3]);
}

__global__ __launch_bounds__(256, 4) void k4_main_cst(
    const float* __restrict__ features, const float* __restrict__ src,
    const float* __restrict__ qs, const float* __restrict__ ks, const float* __restrict__ vs,
    const int* __restrict__ nbr,
    const float* __restrict__ q_b, const float* __restrict__ k_b,
    const float* __restrict__ v_b,
    const unsigned* __restrict__ wH,
    const float* __restrict__ o_b,
    const float* __restrict__ n1_g, const float* __restrict__ n1_b,
    const float* __restrict__ l1_b,
    const float* __restrict__ l2_b,
    const float* __restrict__ n3_g, const float* __restrict__ n3_b,
    const float* __restrict__ fu_b,
    float* __restrict__ fused, float* __restrict__ bnSum, float* __restrict__ bnSq)
{
    __shared__ __align__(16) float A[1024];        // src tile; P5 BN staging
    __shared__ __align__(16) float C[1024];        // running activation f32
    __shared__ __align__(16) float Q[1024];        // q rows (bias applied)
    __shared__ __align__(16) float SC[512];        // attention scores
    __shared__ __align__(16) unsigned BtH[512];    // head_out packed 8x64
    __shared__ __align__(16) unsigned CH[512];     // tgt packed 8x64
    __shared__ __align__(16) unsigned FH[256];     // features packed 8x32
    __shared__ __align__(16) _Float16 Hh[2048];    // ffn hidden f16 8x256
    __shared__ __align__(16) float bK[128], bV[128];
    __shared__ int idxL[128];
    const int tid = threadIdx.x;
    const int r0 = blockIdx.x * 8;

    for (int i = tid; i < 1024; i += 256) A[i] = src[r0 * 128 + i];
    if (tid < 256) {
        float2 f = *(const float2*)(features + r0 * 64 + tid * 2);
        FH[tid] = pack2(f.x, f.y);
    }
    if (tid < 128) {
        idxL[tid] = nbr[r0 * 16 + tid];
        bK[tid] = k_b[tid]; bV[tid] = v_b[tid];
    }
    __syncthreads();
    {   // vectorized Q gather + bias: thread = (row=tid>>5, colgroup=tid&31)
        int r = tid >> 5, cg = tid & 31;
        int i0 = idxL[r * 16];
        float4 qv = make_float4(0.f, 0.f, 0.f, 0.f);
        if (i0 >= 0) qv = *(const float4*)(qs + i0 * 128 + cg * 4);
        float4 qb = *(const float4*)(q_b + cg * 4);
        qv.x += qb.x; qv.y += qb.y; qv.z += qb.z; qv.w += qb.w;
        *(float4*)(&Q[r * 128 + cg * 4]) = qv;
    }
    __syncthreads();

    // ---- phase 1a: scores. thread = (row r, head h, group g of 8) --------
    // s_j = q.(k_j + kb) = q.k_j + q.kb ; q.kb hoisted (same ch for both j).
    const int ar = tid >> 5, ah = (tid >> 3) & 3, ag = tid & 7;
    {
        const int ch = ag & 3;
        float sbias = 0.f;
#pragma unroll
        for (int c4 = 0; c4 < 8; ++c4) {
            float4 qv = *(const float4*)(&Q[ar * 128 + ah * 32 + c4 * 4]);
            float4 kb = *(const float4*)(&bK[ch * 32 + c4 * 4]);
            sbias += qv.x * kb.x + qv.y * kb.y + qv.z * kb.z + qv.w * kb.w;
        }
#pragma unroll
        for (int jj = 0; jj < 2; ++jj) {
            int j = ag + jj * 8;
            int j4 = j >> 2;
            int id = idxL[ar * 16 + ah * 4 + j4];
            float s = 0.f;
            if (id >= 0) {
#pragma unroll
                for (int c4 = 0; c4 < 8; ++c4) {
                    float4 qv = *(const float4*)(&Q[ar * 128 + ah * 32 + c4 * 4]);
                    float4 kv = *(const float4*)(ks + id * 128 + ch * 32 + c4 * 4);
                    s += qv.x * kv.x + qv.y * kv.y + qv.z * kv.z + qv.w * kv.w;
                }
            }
            SC[ar * 64 + ah * 16 + j] = (s + sbias) * 0.08838834764831845f;
        }
    }
    __syncthreads();

    // ---- phase 1b: softmax + P@V (sum w = 1 => +vb once); packed write ---
    {
        float p[16];
        float mx = -3.4e38f;
#pragma unroll
        for (int j = 0; j < 16; ++j) { p[j] = SC[ar * 64 + ah * 16 + j]; mx = fmaxf(mx, p[j]); }
        float sum = 0.f;
#pragma unroll
        for (int j = 0; j < 16; ++j) { p[j] = __expf(p[j] - mx); sum += p[j]; }
        float inv = 1.f / sum;
        float4 acc = make_float4(0.f, 0.f, 0.f, 0.f);
#pragma unroll
        for (int j = 0; j < 16; ++j) {
            int j4 = j >> 2, ch = j & 3;
            int id = idxL[ar * 16 + ah * 4 + j4];
            float w = p[j] * inv;
            if (id >= 0) {
                float4 vv = *(const float4*)(vs + id * 128 + ch * 32 + ag * 4);
                acc.x += w * vv.x; acc.y += w * vv.y;
                acc.z += w * vv.z; acc.w += w * vv.w;
            }
        }
        float4 vb = *(const float4*)(&bV[ah * 32 + ag * 4]);
        acc.x += vb.x; acc.y += vb.y; acc.z += vb.z; acc.w += vb.w;
        BtH[ar * 64 + ah * 16 + ag * 2]     = pack2(acc.x, acc.y);
        BtH[ar * 64 + ah * 16 + ag * 2 + 1] = pack2(acc.z, acc.w);
    }
    __syncthreads();

    // ---- phase 2: C = A + head_out @ o_w + o_b (full K, dot2, uint4 w) ---
    {
        const int c = tid & 127, rh = tid >> 7;
        const unsigned* oH = wH + OFF_O + c * 64;
        float acc[4];
#pragma unroll
        for (int r = 0; r < 4; ++r) acc[r] = 0.f;
        for (int kp4 = 0; kp4 < 16; ++kp4) {
            uint4 w = *(const uint4*)(oH + kp4 * 4);
#pragma unroll
            for (int r = 0; r < 4; ++r) {
                uint4 t = *(const uint4*)(&BtH[(rh * 4 + r) * 64 + kp4 * 4]);
                acc[r] = dot2(t.x, w.x, acc[r]); acc[r] = dot2(t.y, w.y, acc[r]);
                acc[r] = dot2(t.z, w.z, acc[r]); acc[r] = dot2(t.w, w.w, acc[r]);
            }
        }
        const float ob = o_b[c];
#pragma unroll
        for (int r = 0; r < 4; ++r) {
            const int rr = rh * 4 + r;
            C[rr * 128 + c] = A[rr * 128 + c] + ob + acc[r];
        }
    }
    __syncthreads();
    ln_rows8_pack(C, CH, n1_g, n1_b, tid);   // C = tgt (f32 + packed)
    __syncthreads();

    // ---- phase 3: Hh = relu(CH @ l1_w + l1_b)  [8 x 256] f16 out ---------
    {
        const int f = tid;
        const unsigned* l1H = wH + OFF_L1 + f * 64;
        float acc[8];
#pragma unroll
        for (int r = 0; r < 8; ++r) acc[r] = 0.f;
        for (int kp4 = 0; kp4 < 16; ++kp4) {
            uint4 w = *(const uint4*)(l1H + kp4 * 4);
#pragma unroll
            for (int r = 0; r < 8; ++r) {
                uint4 t = *(const uint4*)(&CH[r * 64 + kp4 * 4]);
                acc[r] = dot2(t.x, w.x, acc[r]); acc[r] = dot2(t.y, w.y, acc[r]);
                acc[r] = dot2(t.z, w.z, acc[r]); acc[r] = dot2(t.w, w.w, acc[r]);
            }
        }
        const float bb = l1_b[f];
#pragma unroll
        for (int r = 0; r < 8; ++r) Hh[r * 256 + f] = (_Float16)relu(acc[r] + bb);
    }
    __syncthreads();

    // ---- phase 4: C += Hh @ l2_w + l2_b (full K=256, dot2, uint4 w) ------
    {
        const int c = tid & 127, rh = tid >> 7;
        const unsigned* l2H = wH + OFF_L2 + c * 128;
        const unsigned* HhU = (const unsigned*)Hh;   // 8 x 128 dwords
        float acc[4];
#pragma unroll
        for (int r = 0; r < 4; ++r) acc[r] = 0.f;
        for (int kp4 = 0; kp4 < 32; ++kp4) {
            uint4 w = *(const uint4*)(l2H + kp4 * 4);
#pragma unroll
            for (int r = 0; r < 4; ++r) {
                uint4 t = *(const uint4*)(&HhU[(rh * 4 + r) * 128 + kp4 * 4]);
                acc[r] = dot2(t.x, w.x, acc[r]); acc[r] = dot2(t.y, w.y, acc[r]);
                acc[r] = dot2(t.z, w.z, acc[r]); acc[r] = dot2(t.w, w.w, acc[r]);
            }
        }
        const float lb = l2_b[c];
#pragma unroll
        for (int r = 0; r < 4; ++r) {
            const int rr = rh * 4 + r;
            C[rr * 128 + c] += lb + acc[r];
        }
    }
    __syncthreads();
    ln_rows8_pack(C, CH, n3_g, n3_b, tid);   // C = final tgt (f32 + packed)
    __syncthreads();

    // ---- phase 5: fused = [F, C] @ fu_w + fu_b; BN staging in A ----------
    {
        const int c = tid & 63, rg = tid >> 6;   // 4 groups x 2 rows
        const unsigned* fuH = wH + OFF_FU + c * 96;   // K=192 -> 96 dwords
        float acc[2];
        const float fb = fu_b[c];
#pragma unroll
        for (int r = 0; r < 2; ++r) acc[r] = fb;
        for (int kp4 = 0; kp4 < 8; ++kp4) {      // features half: kp 0..31
            uint4 w = *(const uint4*)(fuH + kp4 * 4);
#pragma unroll
            for (int r = 0; r < 2; ++r) {
                uint4 t = *(const uint4*)(&FH[(rg * 2 + r) * 32 + kp4 * 4]);
                acc[r] = dot2(t.x, w.x, acc[r]); acc[r] = dot2(t.y, w.y, acc[r]);
                acc[r] = dot2(t.z, w.z, acc[r]); acc[r] = dot2(t.w, w.w, acc[r]);
            }
        }
        for (int kp4 = 0; kp4 < 16; ++kp4) {     // tgt half: kp 32..95
            uint4 w = *(const uint4*)(fuH + 32 + kp4 * 4);
#pragma unroll
            for (int r = 0; r < 2; ++r) {
                uint4 t = *(const uint4*)(&CH[(rg * 2 + r) * 64 + kp4 * 4]);
                acc[r] = dot2(t.x, w.x, acc[r]); acc[r] = dot2(t.y, w.y, acc[r]);
                acc[r] = dot2(t.z, w.z, acc[r]); acc[r] = dot2(t.w, w.w, acc[r]);
            }
        }
#pragma unroll
        for (int r = 0; r < 2; ++r) {
            int row = rg * 2 + r;
            float v = acc[r];
            fused[(r0 + row) * 64 + c] = v;
            A[row * 64 + c] = v;
        }
    }
    __syncthreads();
    if (tid < 64) {
        float s = 0.f, s2 = 0.f;
#pragma unroll
        for (int r = 0; r < 8; ++r) { float x = A[r * 64 + tid]; s += x; s2 += x * x; }
        atomicAdd(&bnSum[tid], s);
        atomicAdd(&bnSq[tid], s2);
    }
}

// ---------------------------------------------------------------------------
// K5: batchnorm (train-mode stats) + relu -> fp32 out
// ---------------------------------------------------------------------------
__global__ __launch_bounds__(256) void k5_bn_cst(
    const float* __restrict__ fused, const float* __restrict__ bnSum,
    const float* __restrict__ bnSq,
    const float* __restrict__ g, const float* __restrict__ b,
    float* __restrict__ out, int N)
{
    const int total = N * 64;
    const float invN = 1.f / (float)N;
    for (int i = blockIdx.x * 256 + threadIdx.x; i < total; i += gridDim.x * 256) {
        int c = i & 63;
        float mu = bnSum[c] * invN;
        float var = bnSq[c] * invN - mu * mu;
        float x = fused[i];
        float y = (x - mu) * rsqrtf(var + 1e-3f) * g[c] + b[c];
        out[i] = relu(y);
    }
}

// ---------------------------------------------------------------------------
extern "C" void kernel_launch(void* const* d_in, const int* in_sizes, int n_in,
                              void* d_out, int out_size, void* d_ws, size_t ws_size,
                              hipStream_t stream)
{
    const float* features = (const float*)d_in[0];
    const int*   coords   = (const int*)d_in[1];
    const float* pe_w1 = (const float*)d_in[2];
    const float* pe_b1 = (const float*)d_in[3];
    const float* pe_w2 = (const float*)d_in[4];
    const float* pe_b2 = (const float*)d_in[5];
    const float* in_w  = (const float*)d_in[6];
    const float* in_b  = (const float*)d_in[7];
    const float* q_w   = (const float*)d_in[8];
    const float* q_b   = (const float*)d_in[9];
    const float* k_w   = (const float*)d_in[10];
    const float* k_b   = (const float*)d_in[11];
    const float* v_w   = (const float*)d_in[12];
    const float* v_b   = (const float*)d_in[13];
    const float* o_w   = (const float*)d_in[14];
    const float* o_b   = (const float*)d_in[15];
    const float* n1_g  = (const float*)d_in[16];
    const float* n1_b  = (const float*)d_in[17];
    const float* l1_w  = (const float*)d_in[18];
    const float* l1_b  = (const float*)d_in[19];
    const float* l2_w  = (const float*)d_in[20];
    const float* l2_b  = (const float*)d_in[21];
    const float* n3_g  = (const float*)d_in[22];
    const float* n3_b  = (const float*)d_in[23];
    const float* fu_w  = (const float*)d_in[24];
    const float* fu_b  = (const float*)d_in[25];
    const float* bn_g  = (const float*)d_in[26];
    const float* bn_b  = (const float*)d_in[27];

    const int N = in_sizes[0] / 64;   // 8192

    float* src   = (float*)d_ws;            // N*128
    float* qs    = src + (size_t)N * 128;   // N*128
    float* ks    = qs  + (size_t)N * 128;   // N*128
    float* vs    = ks  + (size_t)N * 128;   // N*128
    float* fused = vs  + (size_t)N * 128;   // N*64
    int*   nbr    = (int*)(fused + (size_t)N * 64);   // N*16 ints
    float* bnSum  = (float*)(nbr + (size_t)N * 16);   // 64
    float* bnSq   = bnSum + 64;                       // 64 (contiguous 128)
    unsigned* wH  = (unsigned*)(bnSq + 64);           // packed weights (~320 KB)

    k0_pack<<<64, 256, 0, stream>>>(q_w, k_w, v_w, o_w, l1_w, l2_w,
                                    in_w, pe_w2, fu_w, wH);
    ka_pre_cst<<<N / 8 + N / 16, 256, 0, stream>>>(features, coords,
                                                   pe_w1, pe_b1, pe_b2, in_b,
                                                   wH,
                                                   src, qs, ks, vs, nbr, bnSum, N);
    k4_main_cst<<<N / 8, 256, 0, stream>>>(features, src, qs, ks, vs, nbr,
                                           q_b, k_b, v_b, wH, o_b, n1_g, n1_b,
                                           l1_b, l2_b, n3_g, n3_b,
                                           fu_b, fused, bnSum, bnSq);
    k5_bn_cst<<<512, 256, 0, stream>>>(fused, bnSum, bnSq, bn_g, bn_b,
                                       (float*)d_out, N);
}

// Round 8
// 207.645 us; speedup vs baseline: 1.1895x; 1.1895x over previous
//
#include <hip/hip_runtime.h>

#define DEVFN __device__ __forceinline__

// NaN-propagating relu (fmaxf(NaN,0)==0 would mask upstream failures).
DEVFN float relu(float x) { return x < 0.f ? 0.f : x; }

// f16 pair helpers: weights/activations packed as half2 in k-major pairs.
// v_dot2_f32_f16: 2 MACs per instr, f32 accumulate.
typedef _Float16 h2 __attribute__((ext_vector_type(2)));
DEVFN float dot2(unsigned a, unsigned b, float c) {
    return __builtin_amdgcn_fdot2(__builtin_bit_cast(h2, a),
                                  __builtin_bit_cast(h2, b), c, false);
}
DEVFN unsigned pack2(float x, float y) {
    h2 h; h.x = (_Float16)x; h.y = (_Float16)y;
    return __builtin_bit_cast(unsigned, h);
}

// Packed-weight layout (round-8: INTERLEAVED TILE [kp4][c][kp_in]):
//   d[kp4*(C*4) + c*4 + (kp&3)] = half2(W[2kp][c], W[2kp+1][c])
// Thread owning col c loads uint4 -> 4 kp pairs, AND lanes c,c+1,... are at
// consecutive 16B addresses -> one coalesced 1KB wave transaction (16 cache
// lines). Round 6 ([kp][c] scalar): 4 lines/instr but 4x the instructions.
// Round 7 ([c][kp] uint4): 4x fewer instrs but 64 lines/instr (stride 256B
// across lanes) -> 4x the line traffic, measured 1.5x SLOWER. This layout
// gets round-6 line traffic with round-7 instruction count.
// Offsets (in dwords) inside the packed-weight workspace region:
#define OFF_Q   0
#define OFF_K   8192
#define OFF_V   16384
#define OFF_O   24576
#define OFF_L1  32768
#define OFF_L2  49152
#define OFF_IN  65536
#define OFF_PE  69632
#define OFF_FU  73728
#define PACKED_TOTAL 79872

// ---------------------------------------------------------------------------
// K0: pack all weight matrices to half2 tiles (runs once before ka).
// ---------------------------------------------------------------------------
__global__ __launch_bounds__(256) void k0_pack(
    const float* __restrict__ q_w, const float* __restrict__ k_w,
    const float* __restrict__ v_w, const float* __restrict__ o_w,
    const float* __restrict__ l1_w, const float* __restrict__ l2_w,
    const float* __restrict__ in_w, const float* __restrict__ pe_w2,
    const float* __restrict__ fu_w, unsigned* __restrict__ dst)
{
    const int gid = blockIdx.x * 256 + threadIdx.x;
    const int stride = gridDim.x * 256;
    auto packmat = [&](const float* s, int K, int C, unsigned* d) {
        const int kp2 = K / 2;        // always divisible by 4 here
        const int n = kp2 * C;
        const int c4 = C * 4;
        for (int i = gid; i < n; i += stride) {
            int kp4 = i / c4;
            int rem = i - kp4 * c4;
            int c = rem >> 2, ki = rem & 3;
            int kp = kp4 * 4 + ki;
            d[i] = pack2(s[(2 * kp) * C + c], s[(2 * kp + 1) * C + c]);
        }
    };
    packmat(q_w, 128, 128, dst + OFF_Q);
    packmat(k_w, 128, 128, dst + OFF_K);
    packmat(v_w, 128, 128, dst + OFF_V);
    packmat(o_w, 128, 128, dst + OFF_O);
    packmat(l1_w, 128, 256, dst + OFF_L1);
    packmat(l2_w, 256, 128, dst + OFF_L2);
    packmat(in_w, 64, 128, dst + OFF_IN);
    packmat(pe_w2, 64, 128, dst + OFF_PE);
    packmat(fu_w, 192, 64, dst + OFF_FU);
}

// ---------------------------------------------------------------------------
// KA: fused pre-work, two block roles interleaved (bx%3): 2/3 src, 1/3 nbr.
//  src role : src = features@in_w+in_b + relu(pe)@pe_w2+pe_b2 ; qs/ks/vs
//  nbr role : neighbor top-16 (manhattan<=4, stable); nbr-block 0 zeros BN.
// Round-6 structure; weight streams = coalesced uint4 tile loads.
// ---------------------------------------------------------------------------
__global__ __launch_bounds__(256, 4) void ka_pre_cst(
    const float* __restrict__ features, const int* __restrict__ coords,
    const float* __restrict__ pe_w1, const float* __restrict__ pe_b1,
    const float* __restrict__ pe_b2,
    const float* __restrict__ in_b,
    const unsigned* __restrict__ wH,          // packed weights
    float* __restrict__ src,
    float* __restrict__ qs, float* __restrict__ ks, float* __restrict__ vs,
    int* __restrict__ nbr, float* __restrict__ bnAcc, int N)
{
    // src-role LDS
    __shared__ __align__(16) float S[1024];       // 8 x 128 src f32
    __shared__ __align__(16) unsigned SH[512];    // 8 x 64 src packed
    __shared__ __align__(16) unsigned FHp[256];   // 8 x 32 features packed
    __shared__ __align__(16) unsigned HHp[256];   // 8 x 32 pe-hidden packed
    __shared__ int   sC[24];
    // nbr-role LDS
    __shared__ int cnt[16];
    __shared__ int lst[16 * 64];
    __shared__ int outL[256];

    const int tid = threadIdx.x;
    const int bx = blockIdx.x;
    const int role_nbr = (bx % 3) == 2;

    if (role_nbr) {
        // ---------------- nbr role: neighbor search -----------------------
        const int nb = bx / 3;
        const int q0 = nb * 16;
        if (nb == 0 && tid < 128) bnAcc[tid] = 0.f;
        if (tid < 16) cnt[tid] = 0;
        outL[tid] = -1;
        __syncthreads();
        int qx[16], qy[16], qz[16];
#pragma unroll
        for (int q = 0; q < 16; ++q) {
            qx[q] = coords[(q0 + q) * 3 + 0];
            qy[q] = coords[(q0 + q) * 3 + 1];
            qz[q] = coords[(q0 + q) * 3 + 2];
        }
        for (int cd = tid; cd < N; cd += 256) {
            int cx = coords[cd * 3 + 0];
            int cy = coords[cd * 3 + 1];
            int cz = coords[cd * 3 + 2];
#pragma unroll
            for (int q = 0; q < 16; ++q) {
                int dx = cx - qx[q]; dx = dx < 0 ? -dx : dx;
                int dy = cy - qy[q]; dy = dy < 0 ? -dy : dy;
                int dz = cz - qz[q]; dz = dz < 0 ? -dz : dz;
                int d = dx + dy + dz;
                if (d <= 4) {
                    int s = atomicAdd(&cnt[q], 1);
                    if (s < 64) lst[q * 64 + s] = (d << 13) | cd;
                }
            }
        }
        __syncthreads();
        {
            const int q = tid >> 4, t = tid & 15;
            int n = cnt[q]; if (n > 64) n = 64;
            for (int e = t; e < n; e += 16) {
                int key = lst[q * 64 + e];
                int rank = 0;
                for (int j = 0; j < n; ++j) rank += (lst[q * 64 + j] < key) ? 1 : 0;
                if (rank < 16) outL[q * 16 + rank] = key & 8191;
            }
        }
        __syncthreads();
        {
            const int q = tid >> 4, t = tid & 15;
            nbr[(q0 + q) * 16 + t] = outL[q * 16 + t];
        }
        return;
    }

    // ---------------- src role: src + q/k/v projections -------------------
    const int sb = (bx / 3) * 2 + (bx % 3);   // 0..1023
    const int r0 = sb * 8;
    if (tid < 24) sC[tid] = coords[r0 * 3 + tid];
    if (tid < 256) {   // features 8x64 -> packed pairs
        float2 f = *(const float2*)(features + r0 * 64 + tid * 2);
        FHp[tid] = pack2(f.x, f.y);
    }
    __syncthreads();
    if (tid < 256) {   // pe hidden, 2 cols per thread, packed
        int r = tid >> 5, t2 = (tid & 31) * 2;
        float v0 = sC[r * 3 + 0] * (1.f / 95.f);
        float v1 = sC[r * 3 + 1] * (1.f / 95.f);
        float v2 = sC[r * 3 + 2] * (1.f / 95.f);
        float h0 = v0 * pe_w1[t2] + v1 * pe_w1[64 + t2] + v2 * pe_w1[128 + t2] + pe_b1[t2];
        float h1 = v0 * pe_w1[t2 + 1] + v1 * pe_w1[64 + t2 + 1] + v2 * pe_w1[128 + t2 + 1] + pe_b1[t2 + 1];
        HHp[tid] = pack2(relu(h0), relu(h1));
    }
    __syncthreads();
    const int c = tid & 127, rh = tid >> 7;
    {
        // src = F@in_w + H@pe_w2 + (in_b + pe_b2); tile uint4 weights
        const unsigned* inH = wH + OFF_IN + c * 4;   // + kp4*512
        const unsigned* peH = wH + OFF_PE + c * 4;
        float acc[4];
        const float base = in_b[c] + pe_b2[c];
#pragma unroll
        for (int r = 0; r < 4; ++r) acc[r] = base;
        for (int kp4 = 0; kp4 < 8; ++kp4) {
            uint4 wi = *(const uint4*)(inH + kp4 * 512);
            uint4 wp = *(const uint4*)(peH + kp4 * 512);
#pragma unroll
            for (int r = 0; r < 4; ++r) {
                const int rr = rh * 4 + r;
                uint4 f = *(const uint4*)(&FHp[rr * 32 + kp4 * 4]);
                uint4 h = *(const uint4*)(&HHp[rr * 32 + kp4 * 4]);
                acc[r] = dot2(f.x, wi.x, acc[r]); acc[r] = dot2(f.y, wi.y, acc[r]);
                acc[r] = dot2(f.z, wi.z, acc[r]); acc[r] = dot2(f.w, wi.w, acc[r]);
                acc[r] = dot2(h.x, wp.x, acc[r]); acc[r] = dot2(h.y, wp.y, acc[r]);
                acc[r] = dot2(h.z, wp.z, acc[r]); acc[r] = dot2(h.w, wp.w, acc[r]);
            }
        }
#pragma unroll
        for (int r = 0; r < 4; ++r) {
            src[(r0 + rh * 4 + r) * 128 + c] = acc[r];
            S[(rh * 4 + r) * 128 + c] = acc[r];
        }
    }
    __syncthreads();
    // pack S -> SH (pairs along the col axis, which is K for q/k/v)
    for (int i = tid; i < 512; i += 256) {
        float2 s = *(const float2*)(&S[i * 2]);
        SH[i] = pack2(s.x, s.y);
    }
    __syncthreads();
    // q/k/v in one pass: 3 coalesced uint4 tile streams, dot2
    {
        const unsigned* qH = wH + OFF_Q + c * 4;   // + kp4*512
        const unsigned* kH = wH + OFF_K + c * 4;
        const unsigned* vH = wH + OFF_V + c * 4;
        float aq[4], ak[4], av[4];
#pragma unroll
        for (int r = 0; r < 4; ++r) { aq[r] = 0.f; ak[r] = 0.f; av[r] = 0.f; }
        for (int kp4 = 0; kp4 < 16; ++kp4) {
            uint4 wq = *(const uint4*)(qH + kp4 * 512);
            uint4 wk = *(const uint4*)(kH + kp4 * 512);
            uint4 wv = *(const uint4*)(vH + kp4 * 512);
#pragma unroll
            for (int r = 0; r < 4; ++r) {
                uint4 s4 = *(const uint4*)(&SH[(rh * 4 + r) * 64 + kp4 * 4]);
                aq[r] = dot2(s4.x, wq.x, aq[r]); aq[r] = dot2(s4.y, wq.y, aq[r]);
                aq[r] = dot2(s4.z, wq.z, aq[r]); aq[r] = dot2(s4.w, wq.w, aq[r]);
                ak[r] = dot2(s4.x, wk.x, ak[r]); ak[r] = dot2(s4.y, wk.y, ak[r]);
                ak[r] = dot2(s4.z, wk.z, ak[r]); ak[r] = dot2(s4.w, wk.w, ak[r]);
                av[r] = dot2(s4.x, wv.x, av[r]); av[r] = dot2(s4.y, wv.y, av[r]);
                av[r] = dot2(s4.z, wv.z, av[r]); av[r] = dot2(s4.w, wv.w, av[r]);
            }
        }
#pragma unroll
        for (int r = 0; r < 4; ++r) {
            qs[(r0 + rh * 4 + r) * 128 + c] = aq[r];
            ks[(r0 + rh * 4 + r) * 128 + c] = ak[r];
            vs[(r0 + rh * 4 + r) * 128 + c] = av[r];
        }
    }
}

// ---------------------------------------------------------------------------
// K4: attention + o-proj + LN1 + FFN + LN2 + fusion + BN partials.
// Round-6 structure; weight streams = coalesced uint4 tile loads.
// ---------------------------------------------------------------------------
DEVFN void ln_rows8_pack(float* Cb, unsigned* CHp, const float* __restrict__ g,
                         const float* __restrict__ b, int tid)
{
    const int r = tid >> 5, l = tid & 31;
    float x[4]; float s = 0.f, s2 = 0.f;
#pragma unroll
    for (int i = 0; i < 4; ++i) {
        x[i] = Cb[r * 128 + l * 4 + i];
        s += x[i]; s2 += x[i] * x[i];
    }
#pragma unroll
    for (int o = 1; o < 32; o <<= 1) { s += __shfl_xor(s, o); s2 += __shfl_xor(s2, o); }
    float mu = s * (1.f / 128.f);
    float var = s2 * (1.f / 128.f) - mu * mu;
    float rstd = rsqrtf(var + 1e-5f);
    float y[4];
#pragma unroll
    for (int i = 0; i < 4; ++i) {
        int cc = l * 4 + i;
        y[i] = (x[i] - mu) * rstd * g[cc] + b[cc];
        Cb[r * 128 + cc] = y[i];
    }
    CHp[r * 64 + l * 2]     = pack2(y[0], y[1]);
    CHp[r * 64 + l * 2 + 1] = pack2(y[2], y[3]);
}

__global__ __launch_bounds__(256, 4) void k4_main_cst(
    const float* __restrict__ features, const float* __restrict__ src,
    const float* __restrict__ qs, const float* __restrict__ ks, const float* __restrict__ vs,
    const int* __restrict__ nbr,
    const float* __restrict__ q_b, const float* __restrict__ k_b,
    const float* __restrict__ v_b,
    const unsigned* __restrict__ wH,
    const float* __restrict__ o_b,
    const float* __restrict__ n1_g, const float* __restrict__ n1_b,
    const float* __restrict__ l1_b,
    const float* __restrict__ l2_b,
    const float* __restrict__ n3_g, const float* __restrict__ n3_b,
    const float* __restrict__ fu_b,
    float* __restrict__ fused, float* __restrict__ bnSum, float* __restrict__ bnSq)
{
    __shared__ __align__(16) float A[1024];        // src tile; P5 BN staging
    __shared__ __align__(16) float C[1024];        // running activation f32
    __shared__ __align__(16) float Q[1024];        // q rows (bias applied)
    __shared__ __align__(16) float SC[512];        // attention scores
    __shared__ __align__(16) unsigned BtH[512];    // head_out packed 8x64
    __shared__ __align__(16) unsigned CH[512];     // tgt packed 8x64
    __shared__ __align__(16) unsigned FH[256];     // features packed 8x32
    __shared__ __align__(16) _Float16 Hh[2048];    // ffn hidden f16 8x256
    __shared__ __align__(16) float bK[128], bV[128];
    __shared__ int idxL[128];
    const int tid = threadIdx.x;
    const int r0 = blockIdx.x * 8;

    for (int i = tid; i < 1024; i += 256) A[i] = src[r0 * 128 + i];
    if (tid < 256) {
        float2 f = *(const float2*)(features + r0 * 64 + tid * 2);
        FH[tid] = pack2(f.x, f.y);
    }
    if (tid < 128) {
        idxL[tid] = nbr[r0 * 16 + tid];
        bK[tid] = k_b[tid]; bV[tid] = v_b[tid];
    }
    __syncthreads();
    {   // vectorized Q gather + bias: thread = (row=tid>>5, colgroup=tid&31)
        int r = tid >> 5, cg = tid & 31;
        int i0 = idxL[r * 16];
        float4 qv = make_float4(0.f, 0.f, 0.f, 0.f);
        if (i0 >= 0) qv = *(const float4*)(qs + i0 * 128 + cg * 4);
        float4 qb = *(const float4*)(q_b + cg * 4);
        qv.x += qb.x; qv.y += qb.y; qv.z += qb.z; qv.w += qb.w;
        *(float4*)(&Q[r * 128 + cg * 4]) = qv;
    }
    __syncthreads();

    // ---- phase 1a: scores. thread = (row r, head h, group g of 8) --------
    // s_j = q.(k_j + kb) = q.k_j + q.kb ; q.kb hoisted (same ch for both j).
    const int ar = tid >> 5, ah = (tid >> 3) & 3, ag = tid & 7;
    {
        const int ch = ag & 3;
        float sbias = 0.f;
#pragma unroll
        for (int c4 = 0; c4 < 8; ++c4) {
            float4 qv = *(const float4*)(&Q[ar * 128 + ah * 32 + c4 * 4]);
            float4 kb = *(const float4*)(&bK[ch * 32 + c4 * 4]);
            sbias += qv.x * kb.x + qv.y * kb.y + qv.z * kb.z + qv.w * kb.w;
        }
#pragma unroll
        for (int jj = 0; jj < 2; ++jj) {
            int j = ag + jj * 8;
            int j4 = j >> 2;
            int id = idxL[ar * 16 + ah * 4 + j4];
            float s = 0.f;
            if (id >= 0) {
#pragma unroll
                for (int c4 = 0; c4 < 8; ++c4) {
                    float4 qv = *(const float4*)(&Q[ar * 128 + ah * 32 + c4 * 4]);
                    float4 kv = *(const float4*)(ks + id * 128 + ch * 32 + c4 * 4);
                    s += qv.x * kv.x + qv.y * kv.y + qv.z * kv.z + qv.w * kv.w;
                }
            }
            SC[ar * 64 + ah * 16 + j] = (s + sbias) * 0.08838834764831845f;
        }
    }
    __syncthreads();

    // ---- phase 1b: softmax + P@V (sum w = 1 => +vb once); packed write ---
    {
        float p[16];
        float mx = -3.4e38f;
#pragma unroll
        for (int j = 0; j < 16; ++j) { p[j] = SC[ar * 64 + ah * 16 + j]; mx = fmaxf(mx, p[j]); }
        float sum = 0.f;
#pragma unroll
        for (int j = 0; j < 16; ++j) { p[j] = __expf(p[j] - mx); sum += p[j]; }
        float inv = 1.f / sum;
        float4 acc = make_float4(0.f, 0.f, 0.f, 0.f);
#pragma unroll
        for (int j = 0; j < 16; ++j) {
            int j4 = j >> 2, ch = j & 3;
            int id = idxL[ar * 16 + ah * 4 + j4];
            float w = p[j] * inv;
            if (id >= 0) {
                float4 vv = *(const float4*)(vs + id * 128 + ch * 32 + ag * 4);
                acc.x += w * vv.x; acc.y += w * vv.y;
                acc.z += w * vv.z; acc.w += w * vv.w;
            }
        }
        float4 vb = *(const float4*)(&bV[ah * 32 + ag * 4]);
        acc.x += vb.x; acc.y += vb.y; acc.z += vb.z; acc.w += vb.w;
        BtH[ar * 64 + ah * 16 + ag * 2]     = pack2(acc.x, acc.y);
        BtH[ar * 64 + ah * 16 + ag * 2 + 1] = pack2(acc.z, acc.w);
    }
    __syncthreads();

    // ---- phase 2: C = A + head_out @ o_w + o_b (tile uint4 w) ------------
    {
        const int c = tid & 127, rh = tid >> 7;
        const unsigned* oH = wH + OFF_O + c * 4;   // + kp4*512
        float acc[4];
#pragma unroll
        for (int r = 0; r < 4; ++r) acc[r] = 0.f;
        for (int kp4 = 0; kp4 < 16; ++kp4) {
            uint4 w = *(const uint4*)(oH + kp4 * 512);
#pragma unroll
            for (int r = 0; r < 4; ++r) {
                uint4 t = *(const uint4*)(&BtH[(rh * 4 + r) * 64 + kp4 * 4]);
                acc[r] = dot2(t.x, w.x, acc[r]); acc[r] = dot2(t.y, w.y, acc[r]);
                acc[r] = dot2(t.z, w.z, acc[r]); acc[r] = dot2(t.w, w.w, acc[r]);
            }
        }
        const float ob = o_b[c];
#pragma unroll
        for (int r = 0; r < 4; ++r) {
            const int rr = rh * 4 + r;
            C[rr * 128 + c] = A[rr * 128 + c] + ob + acc[r];
        }
    }
    __syncthreads();
    ln_rows8_pack(C, CH, n1_g, n1_b, tid);   // C = tgt (f32 + packed)
    __syncthreads();

    // ---- phase 3: Hh = relu(CH @ l1_w + l1_b)  [8 x 256] f16 out ---------
    {
        const int f = tid;
        const unsigned* l1H = wH + OFF_L1 + f * 4;   // + kp4*1024 (C=256)
        float acc[8];
#pragma unroll
        for (int r = 0; r < 8; ++r) acc[r] = 0.f;
        for (int kp4 = 0; kp4 < 16; ++kp4) {
            uint4 w = *(const uint4*)(l1H + kp4 * 1024);
#pragma unroll
            for (int r = 0; r < 8; ++r) {
                uint4 t = *(const uint4*)(&CH[r * 64 + kp4 * 4]);
                acc[r] = dot2(t.x, w.x, acc[r]); acc[r] = dot2(t.y, w.y, acc[r]);
                acc[r] = dot2(t.z, w.z, acc[r]); acc[r] = dot2(t.w, w.w, acc[r]);
            }
        }
        const float bb = l1_b[f];
#pragma unroll
        for (int r = 0; r < 8; ++r) Hh[r * 256 + f] = (_Float16)relu(acc[r] + bb);
    }
    __syncthreads();
    {   // second half of l1 columns (f + 128 handled by same thread? no —
        // 256 threads cover 256 cols in one pass; nothing to do here.)
    }

    // ---- phase 4: C += Hh @ l2_w + l2_b (K=256, tile uint4 w) ------------
    {
        const int c = tid & 127, rh = tid >> 7;
        const unsigned* l2H = wH + OFF_L2 + c * 4;   // + kp4*512, kp4 0..31
        const unsigned* HhU = (const unsigned*)Hh;   // 8 x 128 dwords
        float acc[4];
#pragma unroll
        for (int r = 0; r < 4; ++r) acc[r] = 0.f;
        for (int kp4 = 0; kp4 < 32; ++kp4) {
            uint4 w = *(const uint4*)(l2H + kp4 * 512);
#pragma unroll
            for (int r = 0; r < 4; ++r) {
                uint4 t = *(const uint4*)(&HhU[(rh * 4 + r) * 128 + kp4 * 4]);
                acc[r] = dot2(t.x, w.x, acc[r]); acc[r] = dot2(t.y, w.y, acc[r]);
                acc[r] = dot2(t.z, w.z, acc[r]); acc[r] = dot2(t.w, w.w, acc[r]);
            }
        }
        const float lb = l2_b[c];
#pragma unroll
        for (int r = 0; r < 4; ++r) {
            const int rr = rh * 4 + r;
            C[rr * 128 + c] += lb + acc[r];
        }
    }
    __syncthreads();
    ln_rows8_pack(C, CH, n3_g, n3_b, tid);   // C = final tgt (f32 + packed)
    __syncthreads();

    // ---- phase 5: fused = [F, C] @ fu_w + fu_b; BN staging in A ----------
    {
        const int c = tid & 63, rg = tid >> 6;   // 4 groups x 2 rows
        const unsigned* fuH = wH + OFF_FU + c * 4;   // + kp4*256 (C=64)
        float acc[2];
        const float fb = fu_b[c];
#pragma unroll
        for (int r = 0; r < 2; ++r) acc[r] = fb;
        for (int kp4 = 0; kp4 < 8; ++kp4) {      // features half: kp4 0..7
            uint4 w = *(const uint4*)(fuH + kp4 * 256);
#pragma unroll
            for (int r = 0; r < 2; ++r) {
                uint4 t = *(const uint4*)(&FH[(rg * 2 + r) * 32 + kp4 * 4]);
                acc[r] = dot2(t.x, w.x, acc[r]); acc[r] = dot2(t.y, w.y, acc[r]);
                acc[r] = dot2(t.z, w.z, acc[r]); acc[r] = dot2(t.w, w.w, acc[r]);
            }
        }
        for (int kp4 = 0; kp4 < 16; ++kp4) {     // tgt half: kp4 8..23
            uint4 w = *(const uint4*)(fuH + (8 + kp4) * 256);
#pragma unroll
            for (int r = 0; r < 2; ++r) {
                uint4 t = *(const uint4*)(&CH[(rg * 2 + r) * 64 + kp4 * 4]);
                acc[r] = dot2(t.x, w.x, acc[r]); acc[r] = dot2(t.y, w.y, acc[r]);
                acc[r] = dot2(t.z, w.z, acc[r]); acc[r] = dot2(t.w, w.w, acc[r]);
            }
        }
#pragma unroll
        for (int r = 0; r < 2; ++r) {
            int row = rg * 2 + r;
            float v = acc[r];
            fused[(r0 + row) * 64 + c] = v;
            A[row * 64 + c] = v;
        }
    }
    __syncthreads();
    if (tid < 64) {
        float s = 0.f, s2 = 0.f;
#pragma unroll
        for (int r = 0; r < 8; ++r) { float x = A[r * 64 + tid]; s += x; s2 += x * x; }
        atomicAdd(&bnSum[tid], s);
        atomicAdd(&bnSq[tid], s2);
    }
}

// ---------------------------------------------------------------------------
// K5: batchnorm (train-mode stats) + relu -> fp32 out
// ---------------------------------------------------------------------------
__global__ __launch_bounds__(256) void k5_bn_cst(
    const float* __restrict__ fused, const float* __restrict__ bnSum,
    const float* __restrict__ bnSq,
    const float* __restrict__ g, const float* __restrict__ b,
    float* __restrict__ out, int N)
{
    const int total = N * 64;
    const float invN = 1.f / (float)N;
    for (int i = blockIdx.x * 256 + threadIdx.x; i < total; i += gridDim.x * 256) {
        int c = i & 63;
        float mu = bnSum[c] * invN;
        float var = bnSq[c] * invN - mu * mu;
        float x = fused[i];
        float y = (x - mu) * rsqrtf(var + 1e-3f) * g[c] + b[c];
        out[i] = relu(y);
    }
}

// ---------------------------------------------------------------------------
extern "C" void kernel_launch(void* const* d_in, const int* in_sizes, int n_in,
                              void* d_out, int out_size, void* d_ws, size_t ws_size,
                              hipStream_t stream)
{
    const float* features = (const float*)d_in[0];
    const int*   coords   = (const int*)d_in[1];
    const float* pe_w1 = (const float*)d_in[2];
    const float* pe_b1 = (const float*)d_in[3];
    const float* pe_w2 = (const float*)d_in[4];
    const float* pe_b2 = (const float*)d_in[5];
    const float* in_w  = (const float*)d_in[6];
    const float* in_b  = (const float*)d_in[7];
    const float* q_w   = (const float*)d_in[8];
    const float* q_b   = (const float*)d_in[9];
    const float* k_w   = (const float*)d_in[10];
    const float* k_b   = (const float*)d_in[11];
    const float* v_w   = (const float*)d_in[12];
    const float* v_b   = (const float*)d_in[13];
    const float* o_w   = (const float*)d_in[14];
    const float* o_b   = (const float*)d_in[15];
    const float* n1_g  = (const float*)d_in[16];
    const float* n1_b  = (const float*)d_in[17];
    const float* l1_w  = (const float*)d_in[18];
    const float* l1_b  = (const float*)d_in[19];
    const float* l2_w  = (const float*)d_in[20];
    const float* l2_b  = (const float*)d_in[21];
    const float* n3_g  = (const float*)d_in[22];
    const float* n3_b  = (const float*)d_in[23];
    const float* fu_w  = (const float*)d_in[24];
    const float* fu_b  = (const float*)d_in[25];
    const float* bn_g  = (const float*)d_in[26];
    const float* bn_b  = (const float*)d_in[27];

    const int N = in_sizes[0] / 64;   // 8192

    float* src   = (float*)d_ws;            // N*128
    float* qs    = src + (size_t)N * 128;   // N*128
    float* ks    = qs  + (size_t)N * 128;   // N*128
    float* vs    = ks  + (size_t)N * 128;   // N*128
    float* fused = vs  + (size_t)N * 128;   // N*64
    int*   nbr    = (int*)(fused + (size_t)N * 64);   // N*16 ints
    float* bnSum  = (float*)(nbr + (size_t)N * 16);   // 64
    float* bnSq   = bnSum + 64;                       // 64 (contiguous 128)
    unsigned* wH  = (unsigned*)(bnSq + 64);           // packed weights (~320 KB)

    k0_pack<<<64, 256, 0, stream>>>(q_w, k_w, v_w, o_w, l1_w, l2_w,
                                    in_w, pe_w2, fu_w, wH);
    ka_pre_cst<<<N / 8 + N / 16, 256, 0, stream>>>(features, coords,
                                                   pe_w1, pe_b1, pe_b2, in_b,
                                                   wH,
                                                   src, qs, ks, vs, nbr, bnSum, N);
    k4_main_cst<<<N / 8, 256, 0, stream>>>(features, src, qs, ks, vs, nbr,
                                           q_b, k_b, v_b, wH, o_b, n1_g, n1_b,
                                           l1_b, l2_b, n3_g, n3_b,
                                           fu_b, fused, bnSum, bnSq);
    k5_bn_cst<<<512, 256, 0, stream>>>(fused, bnSum, bnSq, bn_g, bn_b,
                                       (float*)d_out, N);
}